// Round 2
// baseline (227.257 us; speedup 1.0000x reference)
//
#include <hip/hip_runtime.h>
#include <stdint.h>
#include <stddef.h>

typedef short bfrag __attribute__((ext_vector_type(8)));
typedef float f32x4 __attribute__((ext_vector_type(4)));

#define NSEQ 7
// feats packed in MFMA A-fragment order: [btile(1024)][step(18)][lane(64)][j(8)] bf16
// value = feat[btile*16 + (lane&15)][k], k = step*32 + (lane>>4)*8 + j

__constant__ int c_ks[5] = {1, 3, 5, 7, 9};

// per-ksize active MFMA K-steps (B is exactly zero outside): s in [lo, lo+n)
#define SLO0 3
#define SLO1 2
#define SLO2 1
#define SLO3 0
#define SLO4 0
#define SN0 1
#define SN1 3
#define SN2 5
#define SN3 6
#define SN4 7

// LDS layout (halfwords): staging [16][SHW] bf16 (SHW padded to ==24 mod 64 so the
// 16-lane sample-stride A-reads are a free 2-way bank split); max SHW = 664 (L=18).
// pmax int[16*80] (relu'd float bits) at STAGE_MAX_HW.
#define STAGE_MAX_HW 10624
#define XL_HW (STAGE_MAX_HW + 2560)   // 26368 B

static __device__ __forceinline__ unsigned short f2bf(float f) {
  unsigned int u = __float_as_uint(f);
  u += 0x7FFFu + ((u >> 16) & 1u);   // RNE
  return (unsigned short)(u >> 16);
}

// ---------------- prep: pack conv weights + lin1 into B-fragment layout ----------
struct PrepArgs {
  const float* Wk[5];
  const float* lin1_w;
  bfrag* Wpack;
  bfrag* lin1pack;
};

__global__ __launch_bounds__(256) void prep_kernel(PrepArgs a) {
  int tid = blockIdx.x * 256 + threadIdx.x;
  const int NW = NSEQ * 5 * 7 * 64;
  if (tid < NW) {
    int lane = tid & 63, rest = tid >> 6;
    int step = rest % 7, nt = (rest / 7) % 5, seq = rest / 35;
    int quad = lane >> 4, f = lane & 15;
    int ks = c_ks[nt], off = (9 - ks) >> 1;
    const float* W = a.Wk[nt];
    bfrag s;
#pragma unroll
    for (int j = 0; j < 8; ++j) {
      int k = step * 32 + quad * 8 + j;
      int t = k / 24, c = k % 24;
      int tap = t - off;
      float val = 0.f;
      if (c < 20 && tap >= 0 && tap < ks)
        val = W[((seq * 16 + f) * 20 + c) * ks + tap] * 0.2f;  // fold /5
      s[j] = (short)f2bf(val);
    }
    a.Wpack[tid] = s;
  } else if (tid < NW + 4 * 18 * 64) {
    int t2 = tid - NW;
    int lane = t2 & 63, rest = t2 >> 6;
    int step = rest % 18, nt = rest / 18;
    int quad = lane >> 4, col = lane & 15;
    int n = nt * 16 + col;
    bfrag s;
#pragma unroll
    for (int j = 0; j < 8; ++j) {
      int k = step * 32 + quad * 8 + j;
      float val = (k < 560) ? a.lin1_w[n * 560 + k] : 0.f;  // zero rows k>=560 make feats pad inert
      s[j] = (short)f2bf(val);
    }
    a.lin1pack[t2] = s;
  }
}

// ---------------- conv+relu+gmax: sample-tile MFMA, register max over positions ----
struct ConvArgs {
  const float* x[NSEQ];
  const bfrag* Wpack;
  unsigned short* feats;   // packed A-frag layout, see top
};

template <int SLO, int SN>
static __device__ __forceinline__ void mfma_group(f32x4& acc, int s, const bfrag& Af,
                                                  const bfrag* BfBase) {
  if (s >= SLO && s < SLO + SN)
    acc = __builtin_amdgcn_mfma_f32_16x16x32_bf16(Af, BfBase[s - SLO], acc, 0, 0, 0);
}

// One 16-sample MFMA tile over all 5 filter groups. arow = A base (includes quad*8).
static __device__ __forceinline__ void tile_mfma(const unsigned short* arow, const bfrag* Bf,
                                                 f32x4 acc[5]) {
#pragma unroll
  for (int s = 0; s < 7; ++s) {
    bfrag Af = *(const bfrag*)(arow + s * 32);
    mfma_group<SLO0, SN0>(acc[0], s, Af, Bf + 0);
    mfma_group<SLO1, SN1>(acc[1], s, Af, Bf + 1);
    mfma_group<SLO2, SN2>(acc[2], s, Af, Bf + 4);
    mfma_group<SLO3, SN3>(acc[3], s, Af, Bf + 9);
    acc[4] = __builtin_amdgcn_mfma_f32_16x16x32_bf16(Af, Bf[15 + s], acc[4], 0, 0, 0);
  }
}

// M-tile = the block's 16 samples. Each wave sweeps positions l = wave, wave+4, ...;
// per l one tile_mfma, then register fmax into the running per-(sample,filter) max.
// No atomics / shuffles / row-splitting in the inner loop; one 20-op atomicMax merge
// per wave at the end.
template <int L>
__device__ __forceinline__ void conv_body(unsigned short* xl, const ConvArgs& a,
                                          const int seq, const int b0) {
  constexpr int Pv = L + 9;                 // 4 leading pad + L + 5 trailing pad
  constexpr int SHW0 = Pv * 24;
  constexpr int SHW = SHW0 + ((24 - (SHW0 & 63)) & 63);   // == 24 mod 64 halfwords
  constexpr int STAGE_HW = 16 * SHW;
  int* pmax = (int*)(xl + STAGE_MAX_HW);
  const int tid = threadIdx.x;
  const float* xg = a.x[seq];

  // zero staging (covers halo + channel pad) and pmax
  for (int i = tid; i < STAGE_HW / 8; i += 256) ((uint4*)xl)[i] = uint4{0, 0, 0, 0};
  for (int i = tid; i < 320; i += 256) ((uint4*)pmax)[i] = uint4{0, 0, 0, 0};
  __syncthreads();
  // stage x -> bf16 [b][pos=xi+4][c]: one thread per (sample, channel-pair);
  // rows c=2cp and 2cp+1 are contiguous in global; HW packed convert + b32 write.
  for (int r = tid; r < 160; r += 256) {
    int b = r / 10, cp = r - (r / 10) * 10;
    const float* s0 = xg + ((size_t)(b0 + b) * 20 + 2 * cp) * L;
    unsigned short* dst = xl + b * SHW + 4 * 24 + 2 * cp;
#pragma unroll
    for (int xi = 0; xi < L; ++xi) {
      float lo = s0[xi], hi = s0[xi + L];
      unsigned int pk;
      asm("v_cvt_pk_bf16_f32 %0, %1, %2" : "=v"(pk) : "v"(lo), "v"(hi));
      *(unsigned int*)(dst + xi * 24) = pk;   // 4B-aligned: SHW even, 2cp even
    }
  }
  __syncthreads();

  const int wave = tid >> 6, lane = tid & 63, quad = lane >> 4, m = lane & 15;

  // preload the 22 non-zero B fragments for this seq
  const bfrag* wp = a.Wpack + (size_t)(seq * 5 * 7) * 64 + lane;
  bfrag Bf[22];
  {
    int bi = 0;
#pragma unroll
    for (int i = 0; i < SN0; ++i) Bf[bi++] = wp[(0 * 7 + SLO0 + i) * 64];
#pragma unroll
    for (int i = 0; i < SN1; ++i) Bf[bi++] = wp[(1 * 7 + SLO1 + i) * 64];
#pragma unroll
    for (int i = 0; i < SN2; ++i) Bf[bi++] = wp[(2 * 7 + SLO2 + i) * 64];
#pragma unroll
    for (int i = 0; i < SN3; ++i) Bf[bi++] = wp[(3 * 7 + SLO3 + i) * 64];
#pragma unroll
    for (int i = 0; i < SN4; ++i) Bf[bi++] = wp[(4 * 7 + SLO4 + i) * 64];
  }
  // Bf base offsets per nt: {0, 1, 4, 9, 15}

  f32x4 vmax[5];
#pragma unroll
  for (int g = 0; g < 5; ++g) vmax[g] = f32x4{0.f, 0.f, 0.f, 0.f};  // relu folded: max >= 0

  for (int l = wave; l < L; l += 4) {
    // lane m = sample row; window = contiguous 224-hw run starting at l*24
    const unsigned short* arow = &xl[m * SHW + l * 24 + quad * 8];
    f32x4 acc[5];
#pragma unroll
    for (int g = 0; g < 5; ++g) acc[g] = f32x4{0.f, 0.f, 0.f, 0.f};
    tile_mfma(arow, Bf, acc);
#pragma unroll
    for (int g = 0; g < 5; ++g) {
#pragma unroll
      for (int r4 = 0; r4 < 4; ++r4) vmax[g][r4] = fmaxf(vmax[g][r4], acc[g][r4]);
    }
  }

  // merge the 4 waves' running maxima: C row = quad*4 + r4 = sample, col m = filter
#pragma unroll
  for (int g = 0; g < 5; ++g) {
#pragma unroll
    for (int r4 = 0; r4 < 4; ++r4)
      atomicMax(&pmax[(quad * 4 + r4) * 80 + g * 16 + m], __float_as_int(vmax[g][r4]));
  }
  __syncthreads();

  // store phase: 16 samples x 10 chunks of 8 consecutive k -> one 16B store each
  if (tid < 160) {
    int s = tid / 10, c = tid - (tid / 10) * 10;
    int k0 = seq * 80 + c * 8;               // multiple of 8
    bfrag outv;
#pragma unroll
    for (int j = 0; j < 8; ++j)
      outv[j] = (short)f2bf(__int_as_float(pmax[s * 80 + c * 8 + j]));
    int step = k0 >> 5, q = (k0 >> 3) & 3;
    int b = b0 + s;
    *(bfrag*)(a.feats + ((size_t)(b >> 4) * 18 + step) * 512 + (size_t)(q * 16 + (b & 15)) * 8) = outv;
  }
}

__global__ __launch_bounds__(256, 4) void conv_kernel(ConvArgs a) {
  __shared__ __align__(16) unsigned short xl[XL_HW];   // 26368 B
  const int bid = blockIdx.x;
  const int seq = bid % 7;           // interleave seqs across the grid
  const int b0 = (bid / 7) * 16;
  switch (seq) {
    case 0: conv_body<12>(xl, a, 0, b0); break;
    case 1: conv_body< 7>(xl, a, 1, b0); break;
    case 2: conv_body< 8>(xl, a, 2, b0); break;
    case 3: conv_body<16>(xl, a, 3, b0); break;
    case 4: conv_body< 6>(xl, a, 4, b0); break;
    case 5: conv_body< 7>(xl, a, 5, b0); break;
    default: conv_body<18>(xl, a, 6, b0); break;
  }
}

// ---------------- MLP: feats(packed) -> sigmoid(@lin1^T+b1) -> @lin2^T+b2 ----------------
struct MlpArgs {
  const bfrag* feats;      // packed A-frag layout
  const bfrag* lin1pack;
  const float* lin1_b;
  const float* lin2_w;
  const float* lin2_b;
  float* out;
};

__global__ __launch_bounds__(256, 4) void mlp_kernel(MlpArgs a) {
  __shared__ float h[16 * 68];
  __shared__ float w2[64];
  const int tid = threadIdx.x;
  const int b0 = blockIdx.x * 16;
  if (tid < 64) w2[tid] = a.lin2_w[tid];
  const int wave = tid >> 6, lane = tid & 63, quad = lane >> 4, m = lane & 15;
  const int nt = wave;                     // one n-tile per wave
  bfrag Bf[18];
#pragma unroll
  for (int s = 0; s < 18; ++s) Bf[s] = a.lin1pack[(nt * 18 + s) * 64 + lane];
  const bfrag* ap = a.feats + (size_t)blockIdx.x * 18 * 64 + lane;  // coalesced 16B/lane
  f32x4 acc = {0.f, 0.f, 0.f, 0.f};
#pragma unroll
  for (int s = 0; s < 18; ++s)
    acc = __builtin_amdgcn_mfma_f32_16x16x32_bf16(ap[s * 64], Bf[s], acc, 0, 0, 0);
  int n = nt * 16 + m;
  float bias = a.lin1_b[n];
#pragma unroll
  for (int r = 0; r < 4; ++r) {
    float pre = acc[r] + bias;
    h[(quad * 4 + r) * 68 + n] = 1.f / (1.f + __expf(-pre));
  }
  __syncthreads();
  int bl = tid >> 4, q = tid & 15;         // 16 threads per sample, 4 h each
  const float* hr = &h[bl * 68 + q * 4];
  float s = hr[0] * w2[q * 4] + hr[1] * w2[q * 4 + 1] + hr[2] * w2[q * 4 + 2] + hr[3] * w2[q * 4 + 3];
  s += __shfl_xor(s, 1);
  s += __shfl_xor(s, 2);
  s += __shfl_xor(s, 4);
  s += __shfl_xor(s, 8);
  if (q == 0) a.out[b0 + bl] = s + a.lin2_b[0];
}

// ---------------- launch ----------------
extern "C" void kernel_launch(void* const* d_in, const int* in_sizes, int n_in,
                              void* d_out, int out_size, void* d_ws, size_t ws_size,
                              hipStream_t stream) {
  (void)in_sizes; (void)n_in; (void)out_size; (void)ws_size;
  char* ws = (char*)d_ws;
  bfrag* Wpack = (bfrag*)(ws + 0);                 // 15680*16 = 250,880 B
  bfrag* lin1pack = (bfrag*)(ws + 262144);         // 4608*16  =  73,728 B
  unsigned short* feats = (unsigned short*)(ws + 393216);  // 1024*18*64*16 = 18.87 MB

  PrepArgs pa;
  for (int j = 0; j < 5; ++j) pa.Wk[j] = (const float*)d_in[7 + j];
  pa.lin1_w = (const float*)d_in[12];
  pa.Wpack = Wpack;
  pa.lin1pack = lin1pack;
  prep_kernel<<<80, 256, 0, stream>>>(pa);

  ConvArgs ca;
  for (int i = 0; i < NSEQ; ++i) ca.x[i] = (const float*)d_in[i];
  ca.Wpack = Wpack;
  ca.feats = feats;
  // 7168 blocks: 1024 per seq (16 samples each), seqs interleaved by bid%7
  conv_kernel<<<7168, 256, 0, stream>>>(ca);

  MlpArgs ma;
  ma.feats = (const bfrag*)feats;
  ma.lin1pack = lin1pack;
  ma.lin1_b = (const float*)d_in[13];
  ma.lin2_w = (const float*)d_in[14];
  ma.lin2_b = (const float*)d_in[15];
  ma.out = (float*)d_out;
  mlp_kernel<<<1024, 256, 0, stream>>>(ma);
}

// Round 3
// 181.181 us; speedup vs baseline: 1.2543x; 1.2543x over previous
//
#include <hip/hip_runtime.h>
#include <stdint.h>
#include <stddef.h>

typedef short bfrag __attribute__((ext_vector_type(8)));
typedef float f32x4 __attribute__((ext_vector_type(4)));

#define NSEQ 7
// feats packed in MFMA A-fragment order: [btile(1024)][step(18)][lane(64)][j(8)] bf16
// value = feat[btile*16 + (lane&15)][k], k = step*32 + (lane>>4)*8 + j

__constant__ int c_ks[5] = {1, 3, 5, 7, 9};

// per-ksize active MFMA K-steps (B is exactly zero outside): s in [lo, lo+n)
#define SLO0 3
#define SLO1 2
#define SLO2 1
#define SLO3 0
#define SLO4 0
#define SN0 1
#define SN1 3
#define SN2 5
#define SN3 6
#define SN4 7

// LDS layout (halfwords): staging [16][SHW] bf16 (SHW padded to ==24 mod 64 so the
// 16-lane sample-stride A-reads are a free 2-way bank split); max SHW = 664 (L=18).
// pmax int[16*80] (relu'd float bits) at STAGE_MAX_HW.
#define STAGE_MAX_HW 10624
#define XL_HW (STAGE_MAX_HW + 2560)   // 26368 B

static __device__ __forceinline__ unsigned short f2bf(float f) {
  unsigned int u = __float_as_uint(f);
  u += 0x7FFFu + ((u >> 16) & 1u);   // RNE
  return (unsigned short)(u >> 16);
}

// ---------------- prep: pack conv weights + lin1 into B-fragment layout ----------
struct PrepArgs {
  const float* Wk[5];
  const float* lin1_w;
  bfrag* Wpack;
  bfrag* lin1pack;
};

__global__ __launch_bounds__(256) void prep_kernel(PrepArgs a) {
  int tid = blockIdx.x * 256 + threadIdx.x;
  const int NW = NSEQ * 5 * 7 * 64;
  if (tid < NW) {
    int lane = tid & 63, rest = tid >> 6;
    int step = rest % 7, nt = (rest / 7) % 5, seq = rest / 35;
    int quad = lane >> 4, f = lane & 15;
    int ks = c_ks[nt], off = (9 - ks) >> 1;
    const float* W = a.Wk[nt];
    bfrag s;
#pragma unroll
    for (int j = 0; j < 8; ++j) {
      int k = step * 32 + quad * 8 + j;
      int t = k / 24, c = k % 24;
      int tap = t - off;
      float val = 0.f;
      if (c < 20 && tap >= 0 && tap < ks)
        val = W[((seq * 16 + f) * 20 + c) * ks + tap] * 0.2f;  // fold /5
      s[j] = (short)f2bf(val);
    }
    a.Wpack[tid] = s;
  } else if (tid < NW + 4 * 18 * 64) {
    int t2 = tid - NW;
    int lane = t2 & 63, rest = t2 >> 6;
    int step = rest % 18, nt = rest / 18;
    int quad = lane >> 4, col = lane & 15;
    int n = nt * 16 + col;
    bfrag s;
#pragma unroll
    for (int j = 0; j < 8; ++j) {
      int k = step * 32 + quad * 8 + j;
      float val = (k < 560) ? a.lin1_w[n * 560 + k] : 0.f;  // zero rows k>=560 make feats pad inert
      s[j] = (short)f2bf(val);
    }
    a.lin1pack[t2] = s;
  }
}

// ---------------- conv+relu+gmax: sample-tile MFMA, register max over positions ----
struct ConvArgs {
  const float* x[NSEQ];
  const bfrag* Wpack;
  unsigned short* feats;   // packed A-frag layout, see top
};

template <int SLO, int SN>
static __device__ __forceinline__ void mfma_group(f32x4& acc, int s, const bfrag& Af,
                                                  const bfrag* BfBase) {
  if (s >= SLO && s < SLO + SN)
    acc = __builtin_amdgcn_mfma_f32_16x16x32_bf16(Af, BfBase[s - SLO], acc, 0, 0, 0);
}

// One 16-sample MFMA tile over all 5 filter groups. arow = A base (includes quad*8).
static __device__ __forceinline__ void tile_mfma(const unsigned short* arow, const bfrag* Bf,
                                                 f32x4 acc[5]) {
#pragma unroll
  for (int s = 0; s < 7; ++s) {
    bfrag Af = *(const bfrag*)(arow + s * 32);
    mfma_group<SLO0, SN0>(acc[0], s, Af, Bf + 0);
    mfma_group<SLO1, SN1>(acc[1], s, Af, Bf + 1);
    mfma_group<SLO2, SN2>(acc[2], s, Af, Bf + 4);
    mfma_group<SLO3, SN3>(acc[3], s, Af, Bf + 9);
    acc[4] = __builtin_amdgcn_mfma_f32_16x16x32_bf16(Af, Bf[15 + s], acc[4], 0, 0, 0);
  }
}

// M-tile = the block's 16 samples. Each wave sweeps positions l = wave, wave+4, ...;
// per l one tile_mfma, then register fmax into the running per-(sample,filter) max.
// No atomics / shuffles / row-splitting in the inner loop; one 20-op atomicMax merge
// per wave at the end.
// Live set in the hot loop: Bf 88 + acc 20 + vmax 20 + addr/ctrs ~15 ≈ 143 VGPR
// -> needs the 168-VGPR budget of 3 waves/EU; (256,4) caused scratch spills (r2).
template <int L>
__device__ __forceinline__ void conv_body(unsigned short* xl, const ConvArgs& a,
                                          const int seq, const int b0) {
  constexpr int Pv = L + 9;                 // 4 leading pad + L + 5 trailing pad
  constexpr int SHW0 = Pv * 24;
  constexpr int SHW = SHW0 + ((24 - (SHW0 & 63)) & 63);   // == 24 mod 64 halfwords
  constexpr int STAGE_HW = 16 * SHW;
  int* pmax = (int*)(xl + STAGE_MAX_HW);
  const int tid = threadIdx.x;
  const float* xg = a.x[seq];

  // zero staging (covers halo + channel pad) and pmax
  for (int i = tid; i < STAGE_HW / 8; i += 256) ((uint4*)xl)[i] = uint4{0, 0, 0, 0};
  for (int i = tid; i < 320; i += 256) ((uint4*)pmax)[i] = uint4{0, 0, 0, 0};
  __syncthreads();
  // stage x -> bf16 [b][pos=xi+4][c]: one thread per (sample, channel-pair);
  // rows c=2cp and 2cp+1 are contiguous in global; HW packed convert + b32 write.
  for (int r = tid; r < 160; r += 256) {
    int b = r / 10, cp = r - (r / 10) * 10;
    const float* s0 = xg + ((size_t)(b0 + b) * 20 + 2 * cp) * L;
    unsigned short* dst = xl + b * SHW + 4 * 24 + 2 * cp;
#pragma unroll
    for (int xi = 0; xi < L; ++xi) {
      float lo = s0[xi], hi = s0[xi + L];
      unsigned int pk;
      asm("v_cvt_pk_bf16_f32 %0, %1, %2" : "=v"(pk) : "v"(lo), "v"(hi));
      *(unsigned int*)(dst + xi * 24) = pk;   // 4B-aligned: SHW even, 2cp even
    }
  }
  __syncthreads();

  const int wave = tid >> 6, lane = tid & 63, quad = lane >> 4, m = lane & 15;

  // preload the 22 non-zero B fragments for this seq
  const bfrag* wp = a.Wpack + (size_t)(seq * 5 * 7) * 64 + lane;
  bfrag Bf[22];
  {
    int bi = 0;
#pragma unroll
    for (int i = 0; i < SN0; ++i) Bf[bi++] = wp[(0 * 7 + SLO0 + i) * 64];
#pragma unroll
    for (int i = 0; i < SN1; ++i) Bf[bi++] = wp[(1 * 7 + SLO1 + i) * 64];
#pragma unroll
    for (int i = 0; i < SN2; ++i) Bf[bi++] = wp[(2 * 7 + SLO2 + i) * 64];
#pragma unroll
    for (int i = 0; i < SN3; ++i) Bf[bi++] = wp[(3 * 7 + SLO3 + i) * 64];
#pragma unroll
    for (int i = 0; i < SN4; ++i) Bf[bi++] = wp[(4 * 7 + SLO4 + i) * 64];
  }
  // Bf base offsets per nt: {0, 1, 4, 9, 15}

  f32x4 vmax[5];
#pragma unroll
  for (int g = 0; g < 5; ++g) vmax[g] = f32x4{0.f, 0.f, 0.f, 0.f};  // relu folded: max >= 0

  for (int l = wave; l < L; l += 4) {
    // lane m = sample row; window = contiguous 224-hw run starting at l*24
    const unsigned short* arow = &xl[m * SHW + l * 24 + quad * 8];
    f32x4 acc[5];
#pragma unroll
    for (int g = 0; g < 5; ++g) acc[g] = f32x4{0.f, 0.f, 0.f, 0.f};
    tile_mfma(arow, Bf, acc);
#pragma unroll
    for (int g = 0; g < 5; ++g) {
#pragma unroll
      for (int r4 = 0; r4 < 4; ++r4) vmax[g][r4] = fmaxf(vmax[g][r4], acc[g][r4]);
    }
  }

  // merge the 4 waves' running maxima: C row = quad*4 + r4 = sample, col m = filter
#pragma unroll
  for (int g = 0; g < 5; ++g) {
#pragma unroll
    for (int r4 = 0; r4 < 4; ++r4)
      atomicMax(&pmax[(quad * 4 + r4) * 80 + g * 16 + m], __float_as_int(vmax[g][r4]));
  }
  __syncthreads();

  // store phase: 16 samples x 10 chunks of 8 consecutive k -> one 16B store each
  if (tid < 160) {
    int s = tid / 10, c = tid - (tid / 10) * 10;
    int k0 = seq * 80 + c * 8;               // multiple of 8
    bfrag outv;
#pragma unroll
    for (int j = 0; j < 8; ++j)
      outv[j] = (short)f2bf(__int_as_float(pmax[s * 80 + c * 8 + j]));
    int step = k0 >> 5, q = (k0 >> 3) & 3;
    int b = b0 + s;
    *(bfrag*)(a.feats + ((size_t)(b >> 4) * 18 + step) * 512 + (size_t)(q * 16 + (b & 15)) * 8) = outv;
  }
}

__global__ __launch_bounds__(256, 3) void conv_kernel(ConvArgs a) {
  __shared__ __align__(16) unsigned short xl[XL_HW];   // 26368 B
  const int bid = blockIdx.x;
  const int seq = bid % 7;           // interleave seqs across the grid
  const int b0 = (bid / 7) * 16;
  switch (seq) {
    case 0: conv_body<12>(xl, a, 0, b0); break;
    case 1: conv_body< 7>(xl, a, 1, b0); break;
    case 2: conv_body< 8>(xl, a, 2, b0); break;
    case 3: conv_body<16>(xl, a, 3, b0); break;
    case 4: conv_body< 6>(xl, a, 4, b0); break;
    case 5: conv_body< 7>(xl, a, 5, b0); break;
    default: conv_body<18>(xl, a, 6, b0); break;
  }
}

// ---------------- MLP: feats(packed) -> sigmoid(@lin1^T+b1) -> @lin2^T+b2 ----------------
struct MlpArgs {
  const bfrag* feats;      // packed A-frag layout
  const bfrag* lin1pack;
  const float* lin1_b;
  const float* lin2_w;
  const float* lin2_b;
  float* out;
};

__global__ __launch_bounds__(256, 4) void mlp_kernel(MlpArgs a) {
  __shared__ float h[16 * 68];
  __shared__ float w2[64];
  const int tid = threadIdx.x;
  const int b0 = blockIdx.x * 16;
  if (tid < 64) w2[tid] = a.lin2_w[tid];
  const int wave = tid >> 6, lane = tid & 63, quad = lane >> 4, m = lane & 15;
  const int nt = wave;                     // one n-tile per wave
  bfrag Bf[18];
#pragma unroll
  for (int s = 0; s < 18; ++s) Bf[s] = a.lin1pack[(nt * 18 + s) * 64 + lane];
  const bfrag* ap = a.feats + (size_t)blockIdx.x * 18 * 64 + lane;  // coalesced 16B/lane
  f32x4 acc = {0.f, 0.f, 0.f, 0.f};
#pragma unroll
  for (int s = 0; s < 18; ++s)
    acc = __builtin_amdgcn_mfma_f32_16x16x32_bf16(ap[s * 64], Bf[s], acc, 0, 0, 0);
  int n = nt * 16 + m;
  float bias = a.lin1_b[n];
#pragma unroll
  for (int r = 0; r < 4; ++r) {
    float pre = acc[r] + bias;
    h[(quad * 4 + r) * 68 + n] = 1.f / (1.f + __expf(-pre));
  }
  __syncthreads();
  int bl = tid >> 4, q = tid & 15;         // 16 threads per sample, 4 h each
  const float* hr = &h[bl * 68 + q * 4];
  float s = hr[0] * w2[q * 4] + hr[1] * w2[q * 4 + 1] + hr[2] * w2[q * 4 + 2] + hr[3] * w2[q * 4 + 3];
  s += __shfl_xor(s, 1);
  s += __shfl_xor(s, 2);
  s += __shfl_xor(s, 4);
  s += __shfl_xor(s, 8);
  if (q == 0) a.out[b0 + bl] = s + a.lin2_b[0];
}

// ---------------- launch ----------------
extern "C" void kernel_launch(void* const* d_in, const int* in_sizes, int n_in,
                              void* d_out, int out_size, void* d_ws, size_t ws_size,
                              hipStream_t stream) {
  (void)in_sizes; (void)n_in; (void)out_size; (void)ws_size;
  char* ws = (char*)d_ws;
  bfrag* Wpack = (bfrag*)(ws + 0);                 // 15680*16 = 250,880 B
  bfrag* lin1pack = (bfrag*)(ws + 262144);         // 4608*16  =  73,728 B
  unsigned short* feats = (unsigned short*)(ws + 393216);  // 1024*18*64*16 = 18.87 MB

  PrepArgs pa;
  for (int j = 0; j < 5; ++j) pa.Wk[j] = (const float*)d_in[7 + j];
  pa.lin1_w = (const float*)d_in[12];
  pa.Wpack = Wpack;
  pa.lin1pack = lin1pack;
  prep_kernel<<<80, 256, 0, stream>>>(pa);

  ConvArgs ca;
  for (int i = 0; i < NSEQ; ++i) ca.x[i] = (const float*)d_in[i];
  ca.Wpack = Wpack;
  ca.feats = feats;
  // 7168 blocks: 1024 per seq (16 samples each), seqs interleaved by bid%7
  conv_kernel<<<7168, 256, 0, stream>>>(ca);

  MlpArgs ma;
  ma.feats = (const bfrag*)feats;
  ma.lin1pack = lin1pack;
  ma.lin1_b = (const float*)d_in[13];
  ma.lin2_w = (const float*)d_in[14];
  ma.lin2_b = (const float*)d_in[15];
  ma.out = (float*)d_out;
  mlp_kernel<<<1024, 256, 0, stream>>>(ma);
}

// Round 4
// 175.616 us; speedup vs baseline: 1.2941x; 1.0317x over previous
//
#include <hip/hip_runtime.h>
#include <stdint.h>
#include <stddef.h>

typedef short bfrag __attribute__((ext_vector_type(8)));
typedef float f32x4 __attribute__((ext_vector_type(4)));
typedef float f32x4u __attribute__((ext_vector_type(4), aligned(4)));  // rows are only 4B-aligned

#define NSEQ 7
// feats packed in MFMA A-fragment order: [btile(1024)][step(18)][lane(64)][j(8)] bf16
// value = feat[btile*16 + (lane&15)][k], k = step*32 + (lane>>4)*8 + j

__constant__ int c_ks[5] = {1, 3, 5, 7, 9};

// per-ksize active MFMA K-steps (B is exactly zero outside): s in [lo, lo+n)
#define SLO0 3
#define SLO1 2
#define SLO2 1
#define SLO3 0
#define SLO4 0
#define SN0 1
#define SN1 3
#define SN2 5
#define SN3 6
#define SN4 7

// LDS layout (halfwords): staging [32][SHW] bf16 (SHW padded to ==24 mod 64);
// max SHW = 664 (L=18) -> 21248 hw staging; pmax int[32*80] (relu'd float bits) above.
// Total 52736 B -> 3 blocks/CU.
#define STAGE_MAX_HW 21248
#define XL_HW (STAGE_MAX_HW + 5120)

static __device__ __forceinline__ unsigned short f2bf(float f) {
  unsigned int u = __float_as_uint(f);
  u += 0x7FFFu + ((u >> 16) & 1u);   // RNE
  return (unsigned short)(u >> 16);
}

// ---------------- prep: pack conv weights + lin1 into B-fragment layout ----------
struct PrepArgs {
  const float* Wk[5];
  const float* lin1_w;
  bfrag* Wpack;
  bfrag* lin1pack;
};

__global__ __launch_bounds__(256) void prep_kernel(PrepArgs a) {
  int tid = blockIdx.x * 256 + threadIdx.x;
  const int NW = NSEQ * 5 * 7 * 64;
  if (tid < NW) {
    int lane = tid & 63, rest = tid >> 6;
    int step = rest % 7, nt = (rest / 7) % 5, seq = rest / 35;
    int quad = lane >> 4, f = lane & 15;
    int ks = c_ks[nt], off = (9 - ks) >> 1;
    const float* W = a.Wk[nt];
    bfrag s;
#pragma unroll
    for (int j = 0; j < 8; ++j) {
      int k = step * 32 + quad * 8 + j;
      int t = k / 24, c = k % 24;
      int tap = t - off;
      float val = 0.f;
      if (c < 20 && tap >= 0 && tap < ks)
        val = W[((seq * 16 + f) * 20 + c) * ks + tap] * 0.2f;  // fold /5
      s[j] = (short)f2bf(val);
    }
    a.Wpack[tid] = s;
  } else if (tid < NW + 4 * 18 * 64) {
    int t2 = tid - NW;
    int lane = t2 & 63, rest = t2 >> 6;
    int step = rest % 18, nt = rest / 18;
    int quad = lane >> 4, col = lane & 15;
    int n = nt * 16 + col;
    bfrag s;
#pragma unroll
    for (int j = 0; j < 8; ++j) {
      int k = step * 32 + quad * 8 + j;
      float val = (k < 560) ? a.lin1_w[n * 560 + k] : 0.f;  // zero rows k>=560 make feats pad inert
      s[j] = (short)f2bf(val);
    }
    a.lin1pack[t2] = s;
  }
}

// ---------------- conv+relu+gmax: sample-tile MFMA, register max over positions ----
struct ConvArgs {
  const float* x[NSEQ];
  const bfrag* Wpack;
  unsigned short* feats;   // packed A-frag layout, see top
};

template <int SLO, int SN>
static __device__ __forceinline__ void mfma_group(f32x4& acc, int s, const bfrag& Af,
                                                  const bfrag* BfBase) {
  if (s >= SLO && s < SLO + SN)
    acc = __builtin_amdgcn_mfma_f32_16x16x32_bf16(Af, BfBase[s - SLO], acc, 0, 0, 0);
}

// One 16-sample MFMA tile over all 5 filter groups. arow = A base (includes quad*8).
static __device__ __forceinline__ void tile_mfma(const unsigned short* arow, const bfrag* Bf,
                                                 f32x4 acc[5]) {
#pragma unroll
  for (int s = 0; s < 7; ++s) {
    bfrag Af = *(const bfrag*)(arow + s * 32);
    mfma_group<SLO0, SN0>(acc[0], s, Af, Bf + 0);
    mfma_group<SLO1, SN1>(acc[1], s, Af, Bf + 1);
    mfma_group<SLO2, SN2>(acc[2], s, Af, Bf + 4);
    mfma_group<SLO3, SN3>(acc[3], s, Af, Bf + 9);
    acc[4] = __builtin_amdgcn_mfma_f32_16x16x32_bf16(Af, Bf[15 + s], acc[4], 0, 0, 0);
  }
}

// Block = 32 samples of one seq (2 M-tiles of 16). Each wave sweeps positions of
// M-tile 0 then M-tile 1 (vmax reused -> no register growth), register fmax into
// the running per-(sample,filter) max, one 20-op atomicMax merge per wave per tile.
// Live set: Bf 88 + acc 20 + vmax 20 + addr ~15 -> needs 3-waves/EU VGPR budget;
// (256,4) caused scratch spills (r2).
template <int L>
__device__ __forceinline__ void conv_body(unsigned short* xl, const ConvArgs& a,
                                          const int seq, const int b0) {
  constexpr int Pv = L + 9;                 // 4 leading pad + L + 5 trailing pad
  constexpr int SHW0 = Pv * 24;
  constexpr int SHW = SHW0 + ((24 - (SHW0 & 63)) & 63);   // == 24 mod 64 halfwords
  constexpr int STAGE_HW = 32 * SHW;
  constexpr int NC = (L + 3) / 4;           // overlapping float4 chunks per row
  int* pmax = (int*)(xl + STAGE_MAX_HW);
  const int tid = threadIdx.x;
  const float* xg = a.x[seq];

  // zero staging (covers halo + channel pad) and pmax
  for (int i = tid; i < STAGE_HW / 8; i += 256) ((uint4*)xl)[i] = uint4{0, 0, 0, 0};
  for (int i = tid; i < 640; i += 256) ((uint4*)pmax)[i] = uint4{0, 0, 0, 0};
  __syncthreads();
  // stage x -> bf16 [b][pos=xi+4][c]: one job per (sample, channel-pair); rows
  // 2cp and 2cp+1 are contiguous in global. float4 chunks (overlapping tail) cut
  // scattered-load instruction count ~4x vs scalar; HW packed cvt + b32 writes.
  for (int r = tid; r < 320; r += 256) {
    int b = r / 10, cp = r - (r / 10) * 10;
    const float* rowA = xg + ((size_t)(b0 + b) * 20 + 2 * cp) * L;
    unsigned short* dst = xl + b * SHW + 4 * 24 + 2 * cp;
#pragma unroll
    for (int ci = 0; ci < NC; ++ci) {
      constexpr int dummy = 0; (void)dummy;
      int xi0 = (4 * ci > L - 4) ? (L - 4) : 4 * ci;   // compile-time (ci unrolled, L constexpr)
      f32x4u fa = *(const f32x4u*)(rowA + xi0);
      f32x4u fb = *(const f32x4u*)(rowA + L + xi0);
#pragma unroll
      for (int j = 0; j < 4; ++j) {
        unsigned int pk;
        asm("v_cvt_pk_bf16_f32 %0, %1, %2" : "=v"(pk) : "v"(fa[j]), "v"(fb[j]));
        *(unsigned int*)(dst + (xi0 + j) * 24) = pk;   // 4B-aligned: SHW even, 2cp even
      }
    }
  }
  __syncthreads();

  const int wave = tid >> 6, lane = tid & 63, quad = lane >> 4, m = lane & 15;

  // preload the 22 non-zero B fragments for this seq
  const bfrag* wp = a.Wpack + (size_t)(seq * 5 * 7) * 64 + lane;
  bfrag Bf[22];
  {
    int bi = 0;
#pragma unroll
    for (int i = 0; i < SN0; ++i) Bf[bi++] = wp[(0 * 7 + SLO0 + i) * 64];
#pragma unroll
    for (int i = 0; i < SN1; ++i) Bf[bi++] = wp[(1 * 7 + SLO1 + i) * 64];
#pragma unroll
    for (int i = 0; i < SN2; ++i) Bf[bi++] = wp[(2 * 7 + SLO2 + i) * 64];
#pragma unroll
    for (int i = 0; i < SN3; ++i) Bf[bi++] = wp[(3 * 7 + SLO3 + i) * 64];
#pragma unroll
    for (int i = 0; i < SN4; ++i) Bf[bi++] = wp[(4 * 7 + SLO4 + i) * 64];
  }
  // Bf base offsets per nt: {0, 1, 4, 9, 15}

#pragma unroll
  for (int mt = 0; mt < 2; ++mt) {
    f32x4 vmax[5];
#pragma unroll
    for (int g = 0; g < 5; ++g) vmax[g] = f32x4{0.f, 0.f, 0.f, 0.f};  // relu folded: max >= 0

    for (int l = wave; l < L; l += 4) {
      // lane m = sample row within M-tile; window = contiguous run starting at l*24
      const unsigned short* arow = &xl[(mt * 16 + m) * SHW + l * 24 + quad * 8];
      f32x4 acc[5];
#pragma unroll
      for (int g = 0; g < 5; ++g) acc[g] = f32x4{0.f, 0.f, 0.f, 0.f};
      tile_mfma(arow, Bf, acc);
#pragma unroll
      for (int g = 0; g < 5; ++g) {
#pragma unroll
        for (int r4 = 0; r4 < 4; ++r4) vmax[g][r4] = fmaxf(vmax[g][r4], acc[g][r4]);
      }
    }

    // merge the 4 waves' running maxima: C row = quad*4 + r4 = sample, col m = filter
#pragma unroll
    for (int g = 0; g < 5; ++g) {
#pragma unroll
      for (int r4 = 0; r4 < 4; ++r4)
        atomicMax(&pmax[(mt * 16 + quad * 4 + r4) * 80 + g * 16 + m], __float_as_int(vmax[g][r4]));
    }
  }
  __syncthreads();

  // store phase: 32 samples x 10 chunks of 8 consecutive k -> one 16B store each
  for (int r = tid; r < 320; r += 256) {
    int s = r / 10, c = r - (r / 10) * 10;
    int k0 = seq * 80 + c * 8;               // multiple of 8
    bfrag outv;
#pragma unroll
    for (int j = 0; j < 8; ++j)
      outv[j] = (short)f2bf(__int_as_float(pmax[s * 80 + c * 8 + j]));
    int step = k0 >> 5, q = (k0 >> 3) & 3;
    int b = b0 + s;
    *(bfrag*)(a.feats + ((size_t)(b >> 4) * 18 + step) * 512 + (size_t)(q * 16 + (b & 15)) * 8) = outv;
  }
}

__global__ __launch_bounds__(256, 3) void conv_kernel(ConvArgs a) {
  __shared__ __align__(16) unsigned short xl[XL_HW];   // 52736 B
  const int bid = blockIdx.x;
  const int seq = bid % 7;           // interleave seqs across the grid
  const int b0 = (bid / 7) * 32;
  switch (seq) {
    case 0: conv_body<12>(xl, a, 0, b0); break;
    case 1: conv_body< 7>(xl, a, 1, b0); break;
    case 2: conv_body< 8>(xl, a, 2, b0); break;
    case 3: conv_body<16>(xl, a, 3, b0); break;
    case 4: conv_body< 6>(xl, a, 4, b0); break;
    case 5: conv_body< 7>(xl, a, 5, b0); break;
    default: conv_body<18>(xl, a, 6, b0); break;
  }
}

// ---------------- MLP: feats(packed) -> sigmoid(@lin1^T+b1) -> @lin2^T+b2 ----------------
struct MlpArgs {
  const bfrag* feats;      // packed A-frag layout
  const bfrag* lin1pack;
  const float* lin1_b;
  const float* lin2_w;
  const float* lin2_b;
  float* out;
};

__global__ __launch_bounds__(256, 4) void mlp_kernel(MlpArgs a) {
  __shared__ float h[16 * 68];
  __shared__ float w2[64];
  const int tid = threadIdx.x;
  const int b0 = blockIdx.x * 16;
  if (tid < 64) w2[tid] = a.lin2_w[tid];
  const int wave = tid >> 6, lane = tid & 63, quad = lane >> 4, m = lane & 15;
  const int nt = wave;                     // one n-tile per wave
  bfrag Bf[18];
#pragma unroll
  for (int s = 0; s < 18; ++s) Bf[s] = a.lin1pack[(nt * 18 + s) * 64 + lane];
  const bfrag* ap = a.feats + (size_t)blockIdx.x * 18 * 64 + lane;  // coalesced 16B/lane
  f32x4 acc = {0.f, 0.f, 0.f, 0.f};
#pragma unroll
  for (int s = 0; s < 18; ++s)
    acc = __builtin_amdgcn_mfma_f32_16x16x32_bf16(ap[s * 64], Bf[s], acc, 0, 0, 0);
  int n = nt * 16 + m;
  float bias = a.lin1_b[n];
#pragma unroll
  for (int r = 0; r < 4; ++r) {
    float pre = acc[r] + bias;
    h[(quad * 4 + r) * 68 + n] = 1.f / (1.f + __expf(-pre));
  }
  __syncthreads();
  int bl = tid >> 4, q = tid & 15;         // 16 threads per sample, 4 h each
  const float* hr = &h[bl * 68 + q * 4];
  float s = hr[0] * w2[q * 4] + hr[1] * w2[q * 4 + 1] + hr[2] * w2[q * 4 + 2] + hr[3] * w2[q * 4 + 3];
  s += __shfl_xor(s, 1);
  s += __shfl_xor(s, 2);
  s += __shfl_xor(s, 4);
  s += __shfl_xor(s, 8);
  if (q == 0) a.out[b0 + bl] = s + a.lin2_b[0];
}

// ---------------- launch ----------------
extern "C" void kernel_launch(void* const* d_in, const int* in_sizes, int n_in,
                              void* d_out, int out_size, void* d_ws, size_t ws_size,
                              hipStream_t stream) {
  (void)in_sizes; (void)n_in; (void)out_size; (void)ws_size;
  char* ws = (char*)d_ws;
  bfrag* Wpack = (bfrag*)(ws + 0);                 // 15680*16 = 250,880 B
  bfrag* lin1pack = (bfrag*)(ws + 262144);         // 4608*16  =  73,728 B
  unsigned short* feats = (unsigned short*)(ws + 393216);  // 1024*18*64*16 = 18.87 MB

  PrepArgs pa;
  for (int j = 0; j < 5; ++j) pa.Wk[j] = (const float*)d_in[7 + j];
  pa.lin1_w = (const float*)d_in[12];
  pa.Wpack = Wpack;
  pa.lin1pack = lin1pack;
  prep_kernel<<<80, 256, 0, stream>>>(pa);

  ConvArgs ca;
  for (int i = 0; i < NSEQ; ++i) ca.x[i] = (const float*)d_in[i];
  ca.Wpack = Wpack;
  ca.feats = feats;
  // 3584 blocks: 512 per seq (32 samples each), seqs interleaved by bid%7
  conv_kernel<<<3584, 256, 0, stream>>>(ca);

  MlpArgs ma;
  ma.feats = (const bfrag*)feats;
  ma.lin1pack = lin1pack;
  ma.lin1_b = (const float*)d_in[13];
  ma.lin2_w = (const float*)d_in[14];
  ma.lin2_b = (const float*)d_in[15];
  ma.out = (float*)d_out;
  mlp_kernel<<<1024, 256, 0, stream>>>(ma);
}